// Round 10
// baseline (149.379 us; speedup 1.0000x reference)
//
#include <hip/hip_runtime.h>
#include <math.h>

#define GRID_N 256
#define PADN   30
#define GLOB_N 316   // GRID_N + 2*PADN
#define KS     61    // 2*PADN + 1
#define OUT_N  512
#define BATCH  8
#define CHAN   32
#define CPB    8     // channels per sampler block

// Sampler tile: 4 full-width output rows (4x512) per block, CPB channels.
// Deformation bound (analytic, input-independent): pyf in [oy-1.26, oy+1.26],
// gx,gy in [-1,1] => y0 in [oy-2, oy+1], x0 in [0,511].
// Staged window: rows ty-2..ty+5 (8 rows x 512 cols = 16 KB, CONTIGUOUS).
#define STH    4                  // output rows per block
#define SSR    8                  // staged rows
#define SCOLS  512
#define BUFS   4096               // floats per buffer (8*512)
// LDS: 3 buffers = 48 KB -> 3 blocks/CU

typedef float v2f __attribute__((ext_vector_type(2)));

#define GLD16(gaddr, laddr)                                                       \
    __builtin_amdgcn_global_load_lds(                                             \
        (const __attribute__((address_space(1))) void*)(gaddr),                   \
        (__attribute__((address_space(3))) void*)(laddr), 16, 0, 0)

// Two 1D Gaussian factor vectors into LDS (first KS threads).
// make_gaussian(a=1,b=0.5,fwhm1=100,fwhm2=25) is exactly separable:
// kernel[u][v] = g1[u]*g1[v] - 0.5*g2[u]*g2[v].
__device__ __forceinline__ void compute_weights(float* w1, float* w2) {
    int t = threadIdx.x;
    if (t < KS) {
        double d  = (double)(t - PADN);
        double r2 = d * d;
        const double c = 2.772588722239781;  // 4*ln(2)
        w1[t] = (float)exp(-c * r2 / 10000.0); // fwhm1 = 100
        w2[t] = (float)exp(-c * r2 / 625.0);   // fwhm2 = 25
    }
}

// Horizontal separable pass. One block per (batch, global row gi in [0,316)).
__global__ __launch_bounds__(256) void hpass_kernel(const float* __restrict__ xs,
                                                    float* __restrict__ H) {
    __shared__ float srow[GLOB_N];
    __shared__ float w1[KS], w2[KS];
    int b  = blockIdx.x / GLOB_N;
    int gi = blockIdx.x % GLOB_N;
    int t  = threadIdx.x;

    compute_weights(w1, w2);

    int iy = gi - PADN;
    iy = iy < 0 ? 0 : (iy > GRID_N - 1 ? GRID_N - 1 : iy);
    const float* src = xs + ((size_t)b * GRID_N + iy) * GRID_N;
    for (int j = t; j < GLOB_N; j += 256) {
        int ix = j - PADN;
        ix = ix < 0 ? 0 : (ix > GRID_N - 1 ? GRID_N - 1 : ix);
        srow[j] = src[ix];
    }
    __syncthreads();

    float a1 = 0.f, a2 = 0.f, a3 = 0.f, a4 = 0.f;
    for (int v = 0; v < KS; ++v) {
        float s  = srow[t + v];
        float cc = (float)(t + v - PADN) * (1.0f / 255.0f);
        float cs = cc * s;
        float cw1 = w1[v], cw2 = w2[v];
        a1 += cw1 * s;
        a2 += cw2 * s;
        a3 += cw1 * cs;
        a4 += cw2 * cs;
    }
    size_t cst  = (size_t)GLOB_N * GRID_N;
    size_t base = ((size_t)(b * 4) * GLOB_N + gi) * GRID_N + t;
    H[base]           = a1;
    H[base + cst]     = a2;
    H[base + 2 * cst] = a3;
    H[base + 3 * cst] = a4;
}

// Vertical pass + normalize + clip, register sliding window: each thread
// accumulates 4 consecutive output rows over one 64-row sweep of H
// (3.8x less L2 traffic than per-row blocks). 512 blocks, XCD chunk 64.
__global__ __launch_bounds__(256) void vpass_kernel(const float* __restrict__ H,
                                                    float* __restrict__ g256) {
    __shared__ float w1[KS], w2[KS];
    int bid = (int)blockIdx.x;
    bid = (bid & 7) * 64 + (bid >> 3);
    int b  = bid >> 6;
    int y0 = (bid & 63) * 4;
    int t = threadIdx.x;

    compute_weights(w1, w2);
    __syncthreads();

    const float* Hb = H + (size_t)b * 4 * GLOB_N * GRID_N;
    size_t cst = (size_t)GLOB_N * GRID_N;

    float s1[4], s2[4], sx1[4], sx2[4], sy1[4], sy2[4];
    #pragma unroll
    for (int dy = 0; dy < 4; ++dy) {
        s1[dy] = s2[dy] = sx1[dy] = sx2[dy] = sy1[dy] = sy2[dy] = 0.f;
    }

    for (int u = 0; u < KS + 3; ++u) {
        size_t off = (size_t)(y0 + u) * GRID_N + t;
        float h1 = Hb[off];
        float h2 = Hb[off + cst];
        float h3 = Hb[off + 2 * cst];
        float h4 = Hb[off + 3 * cst];
        float cc = (float)(y0 + u - PADN) * (1.0f / 255.0f);
        float ch1 = cc * h1, ch2 = cc * h2;
        #pragma unroll
        for (int dy = 0; dy < 4; ++dy) {
            int k = u - dy;
            if (k >= 0 && k < KS) {
                float a = w1[k], bw = w2[k];
                s1[dy]  += a * h1;  s2[dy]  += bw * h2;
                sx1[dy] += a * h3;  sx2[dy] += bw * h4;
                sy1[dy] += a * ch1; sy2[dy] += bw * ch2;
            }
        }
    }

    #pragma unroll
    for (int dy = 0; dy < 4; ++dy) {
        float p  = s1[dy] - 0.5f * s2[dy];
        float xf = (sx1[dy] - 0.5f * sx2[dy]) / p;
        float yf = (sy1[dy] - 0.5f * sy2[dy]) / p;
        float xg = fminf(fmaxf(xf * 2.0f - 1.0f, -1.0f), 1.0f);
        float yg = fminf(fmaxf(yf * 2.0f - 1.0f, -1.0f), 1.0f);
        size_t o = (size_t)(b * 2) * GRID_N * GRID_N + (size_t)(y0 + dy) * GRID_N + t;
        g256[o] = xg;
        g256[o + (size_t)GRID_N * GRID_N] = yg;
    }
}

// 2x bilinear upsample, jax.image.resize half-pixel semantics.
__global__ __launch_bounds__(256) void upsample_kernel(const float* __restrict__ g256,
                                                       float* __restrict__ gup) {
    int idx = blockIdx.x * 256 + threadIdx.x;
    int ox = idx & (OUT_N - 1);
    int oy = (idx >> 9) & (OUT_N - 1);
    int b  = idx >> 18;

    float sx = 0.5f * (float)ox - 0.25f;
    float sy = 0.5f * (float)oy - 0.25f;
    float fxf = floorf(sx), fyf = floorf(sy);
    int x0 = (int)fxf, y0 = (int)fyf;
    float fx = sx - fxf, fy = sy - fyf;
    int x0c = x0 < 0 ? 0 : x0;
    int x1c = x0 + 1 > GRID_N - 1 ? GRID_N - 1 : x0 + 1;
    int y0c = y0 < 0 ? 0 : y0;
    int y1c = y0 + 1 > GRID_N - 1 ? GRID_N - 1 : y0 + 1;

    for (int c = 0; c < 2; ++c) {
        const float* g = g256 + ((size_t)(b * 2 + c)) * GRID_N * GRID_N;
        float v00 = g[y0c * GRID_N + x0c];
        float v10 = g[y0c * GRID_N + x1c];
        float v01 = g[y1c * GRID_N + x0c];
        float v11 = g[y1c * GRID_N + x1c];
        float v = (v00 * (1.f - fx) + v10 * fx) * (1.f - fy)
                + (v01 * (1.f - fx) + v11 * fx) * fy;
        gup[((size_t)(b * 2 + c)) * OUT_N * OUT_N + (size_t)oy * OUT_N + ox] = v;
    }
}

// grid_sample bilinear via contiguous DMA-staged row bands, 3-buffer ring,
// ONE barrier per channel: staging c+2 right after the iter-c barrier is safe
// (all waves passing it finished gather(c-1), the last reader of buf (c+2)%3).
__global__ __launch_bounds__(256) void sample_kernel(const float* __restrict__ x,
                                                     const float* __restrict__ gup,
                                                     float* __restrict__ out) {
    __shared__ float tile[3 * BUFS];   // 48 KB

    int bid = (int)blockIdx.x;
    // 4096 blocks; chunk 512 -> XCD k owns batch k; row-groups sweep fastest.
    bid = (bid & 7) * 512 + (bid >> 3);
    int b  = bid >> 9;
    int cg = (bid >> 7) & 3;
    int rg = bid & 127;
    int ty = rg * STH;
    int c0 = cg * CPB;

    int t  = threadIdx.x;
    int r  = t >> 6;          // output row 0..3 within the band
    int cb = (t & 63) * 2;    // column pair base

    // ---- per-thread DMA source offsets (channel-invariant, contiguous) ----
    // slot = k*256 + t: srow = 2k + (t>>7), scol = (t&127)*4.
    int goff[4];
    {
        int baserow = ty - 2 + (t >> 7);
        int scol = (t & 127) * 4;
        #pragma unroll
        for (int k = 0; k < 4; ++k) {
            int rr = baserow + 2 * k;
            rr = rr < 0 ? 0 : (rr > OUT_N - 1 ? OUT_N - 1 : rr);
            goff[k] = rr * OUT_N + scol;
        }
    }
    int wb0 = (t & ~63);       // wave-uniform slot base

    // ---- per-px bilinear weights + LDS base indices (channel-invariant) ----
    float w00[8], w10[8], w01[8], w11[8];
    int lbase[8];
    int oy = ty + r;
    {
        size_t gplane = (size_t)OUT_N * OUT_N;
        size_t grow = (size_t)(b * 2) * gplane + (size_t)oy * OUT_N;
        float by = -1.0f + (float)oy * (2.0f / 511.0f);
        #pragma unroll
        for (int k = 0; k < 4; ++k) {
            #pragma unroll
            for (int h = 0; h < 2; ++h) {
                int j = k * 2 + h;
                int ox = 128 * k + cb + h;
                float gxu = gup[grow + ox];
                float gyu = gup[grow + ox + gplane];
                float bx = -1.0f + (float)ox * (2.0f / 511.0f);
                float gx = (49.0f * bx + gxu) * 0.02f;
                float gy = (49.0f * by + gyu) * 0.02f;
                float pxf = (gx + 1.0f) * 255.5f;  // in [0,511]
                float pyf = (gy + 1.0f) * 255.5f;
                float fx0 = floorf(pxf), fy0 = floorf(pyf);
                int x0 = (int)fx0, y0 = (int)fy0;
                float fx = pxf - fx0, fy = pyf - fy0;
                w00[j] = (1.f - fx) * (1.f - fy);
                w10[j] = fx * (1.f - fy);
                w01[j] = (1.f - fx) * fy;
                w11[j] = fx * fy;
                lbase[j] = (y0 - (ty - 2)) * SCOLS + x0;   // slot row 2..6
            }
        }
    }

    size_t plane = (size_t)OUT_N * OUT_N;
    const float* xb = x + ((size_t)b * CHAN + c0) * plane;
    float* ob = out + ((size_t)b * CHAN + c0) * plane;
    size_t orow = (size_t)oy * OUT_N;

    // buffer for channel c = c % 3
    #define STAGE(c)                                                             \
        do {                                                                     \
            const float* xc_ = xb + (size_t)(c) * plane;                         \
            float* lb_ = &tile[((c) % 3) * BUFS];                                \
            _Pragma("unroll")                                                    \
            for (int k_ = 0; k_ < 4; ++k_)                                       \
                GLD16(xc_ + goff[k_], lb_ + (k_ * 256 + wb0) * 4);               \
        } while (0)

    STAGE(0);
    STAGE(1);

    for (int c = 0; c < CPB; ++c) {
        // In-order vmcnt: wait for stage(c); younger outstanding ops counted:
        // steady: stores(c-2)[4] + stage(c+1)[4] + stores(c-1)[4] = 12;
        // c=0: stage(1) -> 4; c=1: stage(2)+stores(0) -> 8;
        // c=CPB-1: stores(c-3 tail gone) stores(c-2)? -> stage issued at c-2;
        //          younger = stores(CPB-3)[4]+stores(CPB-2)[4] = 8.
        if (c == 0)                 asm volatile("s_waitcnt vmcnt(4)" ::: "memory");
        else if (c == 1 || c == CPB - 1) asm volatile("s_waitcnt vmcnt(8)" ::: "memory");
        else                        asm volatile("s_waitcnt vmcnt(12)" ::: "memory");
        __builtin_amdgcn_s_barrier();          // loads(c) landed; gather(c-1) done by all
        __builtin_amdgcn_sched_barrier(0);

        if (c + 2 < CPB) STAGE(c + 2);         // overwrites buf (c+2)%3: safe now

        const float* tb_ = &tile[(c % 3) * BUFS];
        float* oc = ob + (size_t)c * plane;
        #pragma unroll
        for (int k = 0; k < 4; ++k) {
            float vv0, vv1;
            {
                int j = k * 2;
                int lb = lbase[j];
                vv0 = w00[j] * tb_[lb] + w10[j] * tb_[lb + 1]
                    + w01[j] * tb_[lb + SCOLS] + w11[j] * tb_[lb + SCOLS + 1];
            }
            {
                int j = k * 2 + 1;
                int lb = lbase[j];
                vv1 = w00[j] * tb_[lb] + w10[j] * tb_[lb + 1]
                    + w01[j] * tb_[lb + SCOLS] + w11[j] * tb_[lb + SCOLS + 1];
            }
            v2f st; st.x = vv0; st.y = vv1;
            __builtin_nontemporal_store(st, (v2f*)(oc + orow + cb + 128 * k));
        }
        __builtin_amdgcn_sched_barrier(0);
    }
    #undef STAGE
}

extern "C" void kernel_launch(void* const* d_in, const int* in_sizes, int n_in,
                              void* d_out, int out_size, void* d_ws, size_t ws_size,
                              hipStream_t stream) {
    (void)in_sizes; (void)n_in; (void)d_ws; (void)ws_size; (void)out_size;
    const float* x  = (const float*)d_in[0];   // (8,32,512,512)
    const float* xs = (const float*)d_in[1];   // (8,1,256,256)
    // d_in[2] = gauss_kernel: recomputed analytically (separable form).

    float* out = (float*)d_out;
    const size_t XS_OUT = (size_t)BATCH * CHAN * OUT_N * OUT_N;  // 67,108,864
    float* gup = out + XS_OUT;  // output 1: grid_up (8,2,512,512)

    // Scratch lives in the x_sampled region of d_out; fully overwritten by
    // sample_kernel (which runs after its consumers).
    float* H    = out;                     // 8*4*316*256 = 2,588,672 floats
    float* g256 = out + 4u * 1024 * 1024;  // 8*2*256*256 = 1,048,576 floats

    hipLaunchKernelGGL(hpass_kernel, dim3(BATCH * GLOB_N), dim3(256), 0, stream, xs, H);
    hipLaunchKernelGGL(vpass_kernel, dim3(BATCH * GRID_N / 4), dim3(256), 0, stream, H, g256);
    hipLaunchKernelGGL(upsample_kernel, dim3(BATCH * OUT_N * OUT_N / 256), dim3(256), 0, stream,
                       g256, gup);
    const int SBLOCKS = BATCH * (CHAN / CPB) * (OUT_N / STH);   // 4096
    hipLaunchKernelGGL(sample_kernel, dim3(SBLOCKS), dim3(256), 0, stream, x, gup, out);
}

// Round 11
// 138.896 us; speedup vs baseline: 1.0755x; 1.0755x over previous
//
#include <hip/hip_runtime.h>
#include <math.h>

#define GRID_N 256
#define PADN   30
#define GLOB_N 316   // GRID_N + 2*PADN
#define KS     61    // 2*PADN + 1
#define OUT_N  512
#define BATCH  8
#define CHAN   32
#define CPB    16    // channels per sampler block

// Sampler tile: 4 full-width output rows (4x512) per block, CPB channels.
// Deformation bound (analytic, input-independent): pyf in [oy-1.26, oy+1.26],
// gx,gy in [-1,1] => y0 in [oy-2, oy+1], x0 in [0,511].
// Staged window: rows ty-2..ty+5 (8 rows x 512 cols = 16 KB, CONTIGUOUS).
#define STH    4                  // output rows per block
#define SSR    8                  // staged rows
#define SCOLS  512
#define SLOTS  1024               // float4 slots per buffer (= SSR*SCOLS/4)
#define BUFS   4160               // floats per buffer incl. 64-float pad
// LDS: 2*BUFS*4 = 33,280 B -> 4 blocks/CU

typedef float v2f __attribute__((ext_vector_type(2)));

#define GLD16(gaddr, laddr)                                                       \
    __builtin_amdgcn_global_load_lds(                                             \
        (const __attribute__((address_space(1))) void*)(gaddr),                   \
        (__attribute__((address_space(3))) void*)(laddr), 16, 0, 0)

// Two 1D Gaussian factor vectors into LDS (first KS threads).
// make_gaussian(a=1,b=0.5,fwhm1=100,fwhm2=25) is exactly separable:
// kernel[u][v] = g1[u]*g1[v] - 0.5*g2[u]*g2[v].
__device__ __forceinline__ void compute_weights(float* w1, float* w2) {
    int t = threadIdx.x;
    if (t < KS) {
        double d  = (double)(t - PADN);
        double r2 = d * d;
        const double c = 2.772588722239781;  // 4*ln(2)
        w1[t] = (float)exp(-c * r2 / 10000.0); // fwhm1 = 100
        w2[t] = (float)exp(-c * r2 / 625.0);   // fwhm2 = 25
    }
}

// Horizontal separable pass. One block per (batch, global row gi in [0,316)).
__global__ __launch_bounds__(256) void hpass_kernel(const float* __restrict__ xs,
                                                    float* __restrict__ H) {
    __shared__ float srow[GLOB_N];
    __shared__ float w1[KS], w2[KS];
    int b  = blockIdx.x / GLOB_N;
    int gi = blockIdx.x % GLOB_N;
    int t  = threadIdx.x;

    compute_weights(w1, w2);

    int iy = gi - PADN;
    iy = iy < 0 ? 0 : (iy > GRID_N - 1 ? GRID_N - 1 : iy);
    const float* src = xs + ((size_t)b * GRID_N + iy) * GRID_N;
    for (int j = t; j < GLOB_N; j += 256) {
        int ix = j - PADN;
        ix = ix < 0 ? 0 : (ix > GRID_N - 1 ? GRID_N - 1 : ix);
        srow[j] = src[ix];
    }
    __syncthreads();

    float a1 = 0.f, a2 = 0.f, a3 = 0.f, a4 = 0.f;
    for (int v = 0; v < KS; ++v) {
        float s  = srow[t + v];
        float cc = (float)(t + v - PADN) * (1.0f / 255.0f);
        float cs = cc * s;
        float cw1 = w1[v], cw2 = w2[v];
        a1 += cw1 * s;
        a2 += cw2 * s;
        a3 += cw1 * cs;
        a4 += cw2 * cs;
    }
    size_t cst  = (size_t)GLOB_N * GRID_N;
    size_t base = ((size_t)(b * 4) * GLOB_N + gi) * GRID_N + t;
    H[base]           = a1;
    H[base + cst]     = a2;
    H[base + 2 * cst] = a3;
    H[base + 3 * cst] = a4;
}

// Vertical pass + normalize + clip. XCD-swizzled (chunk 256 = one batch/XCD).
__global__ __launch_bounds__(256) void vpass_kernel(const float* __restrict__ H,
                                                    float* __restrict__ g256) {
    __shared__ float w1[KS], w2[KS];
    int bid = (int)blockIdx.x;
    bid = (bid & 7) * 256 + (bid >> 3);
    int b = bid >> 8;
    int y = bid & 255;
    int t = threadIdx.x;

    compute_weights(w1, w2);
    __syncthreads();

    const float* Hb = H + (size_t)b * 4 * GLOB_N * GRID_N;
    size_t cst = (size_t)GLOB_N * GRID_N;

    float s1 = 0.f, s2 = 0.f, sx1 = 0.f, sx2 = 0.f, sy1 = 0.f, sy2 = 0.f;
    for (int u = 0; u < KS; ++u) {
        size_t off = (size_t)(y + u) * GRID_N + t;
        float h1 = Hb[off];
        float h2 = Hb[off + cst];
        float h3 = Hb[off + 2 * cst];
        float h4 = Hb[off + 3 * cst];
        float cw1 = w1[u], cw2 = w2[u];
        float cc = (float)(y + u - PADN) * (1.0f / 255.0f);
        s1  += cw1 * h1;
        s2  += cw2 * h2;
        sx1 += cw1 * h3;
        sx2 += cw2 * h4;
        sy1 += cw1 * (cc * h1);
        sy2 += cw2 * (cc * h2);
    }
    float p  = s1 - 0.5f * s2;
    float xf = (sx1 - 0.5f * sx2) / p;
    float yf = (sy1 - 0.5f * sy2) / p;
    float xg = fminf(fmaxf(xf * 2.0f - 1.0f, -1.0f), 1.0f);
    float yg = fminf(fmaxf(yf * 2.0f - 1.0f, -1.0f), 1.0f);

    size_t o = (size_t)(b * 2) * GRID_N * GRID_N + (size_t)y * GRID_N + t;
    g256[o] = xg;
    g256[o + (size_t)GRID_N * GRID_N] = yg;
}

// 2x bilinear upsample, jax.image.resize half-pixel semantics.
__global__ __launch_bounds__(256) void upsample_kernel(const float* __restrict__ g256,
                                                       float* __restrict__ gup) {
    int idx = blockIdx.x * 256 + threadIdx.x;
    int ox = idx & (OUT_N - 1);
    int oy = (idx >> 9) & (OUT_N - 1);
    int b  = idx >> 18;

    float sx = 0.5f * (float)ox - 0.25f;
    float sy = 0.5f * (float)oy - 0.25f;
    float fxf = floorf(sx), fyf = floorf(sy);
    int x0 = (int)fxf, y0 = (int)fyf;
    float fx = sx - fxf, fy = sy - fyf;
    int x0c = x0 < 0 ? 0 : x0;
    int x1c = x0 + 1 > GRID_N - 1 ? GRID_N - 1 : x0 + 1;
    int y0c = y0 < 0 ? 0 : y0;
    int y1c = y0 + 1 > GRID_N - 1 ? GRID_N - 1 : y0 + 1;

    for (int c = 0; c < 2; ++c) {
        const float* g = g256 + ((size_t)(b * 2 + c)) * GRID_N * GRID_N;
        float v00 = g[y0c * GRID_N + x0c];
        float v10 = g[y0c * GRID_N + x1c];
        float v01 = g[y1c * GRID_N + x0c];
        float v11 = g[y1c * GRID_N + x1c];
        float v = (v00 * (1.f - fx) + v10 * fx) * (1.f - fy)
                + (v01 * (1.f - fx) + v11 * fx) * fy;
        gup[((size_t)(b * 2 + c)) * OUT_N * OUT_N + (size_t)oy * OUT_N + ox] = v;
    }
}

// grid_sample bilinear via CONTIGUOUS DMA-staged row bands.
// Block = 4 full-width output rows x CPB channels. Per channel: one
// contiguous 16 KB fetch (8 rows x 512) via 4 global_load_lds calls/wave,
// LDS gather, dwordx2 nontemporal stores. Counted vmcnt, raw barriers.
__global__ __launch_bounds__(256) void sample_kernel(const float* __restrict__ x,
                                                     const float* __restrict__ gup,
                                                     float* __restrict__ out) {
    __shared__ float tile[2 * BUFS];   // 33,280 B

    int bid = (int)blockIdx.x;
    // 2048 blocks; chunk 256 -> XCD k owns batch k; row-groups sweep fastest.
    bid = (bid & 7) * 256 + (bid >> 3);
    int b  = bid >> 8;
    int cg = (bid >> 7) & 1;
    int rg = bid & 127;
    int ty = rg * STH;
    int c0 = cg * CPB;

    int t  = threadIdx.x;
    int r  = t >> 6;          // output row 0..3 within the band
    int cb = (t & 63) * 2;    // column pair base

    // ---- per-thread DMA source offsets (channel-invariant, contiguous) ----
    // slot = k*256 + t: srow = 2k + (t>>7), scol = (t&127)*4.
    int goff[4];
    {
        int baserow = ty - 2 + (t >> 7);
        int scol = (t & 127) * 4;
        #pragma unroll
        for (int k = 0; k < 4; ++k) {
            int rr = baserow + 2 * k;
            rr = rr < 0 ? 0 : (rr > OUT_N - 1 ? OUT_N - 1 : rr);
            goff[k] = rr * OUT_N + scol;
        }
    }
    int wb0 = (t & ~63);       // wave-uniform slot base

    // ---- per-px bilinear weights + LDS base indices (channel-invariant) ----
    // Thread's 8 px: ox = 128*k + cb + h, oy = ty + r.
    float w00[8], w10[8], w01[8], w11[8];
    int lbase[8];
    int oy = ty + r;
    {
        size_t gplane = (size_t)OUT_N * OUT_N;
        size_t grow = (size_t)(b * 2) * gplane + (size_t)oy * OUT_N;
        float by = -1.0f + (float)oy * (2.0f / 511.0f);
        #pragma unroll
        for (int k = 0; k < 4; ++k) {
            #pragma unroll
            for (int h = 0; h < 2; ++h) {
                int j = k * 2 + h;
                int ox = 128 * k + cb + h;
                float gxu = gup[grow + ox];
                float gyu = gup[grow + ox + gplane];
                float bx = -1.0f + (float)ox * (2.0f / 511.0f);
                float gx = (49.0f * bx + gxu) * 0.02f;
                float gy = (49.0f * by + gyu) * 0.02f;
                float pxf = (gx + 1.0f) * 255.5f;  // in [0,511]
                float pyf = (gy + 1.0f) * 255.5f;
                float fx0 = floorf(pxf), fy0 = floorf(pyf);
                int x0 = (int)fx0, y0 = (int)fy0;
                float fx = pxf - fx0, fy = pyf - fy0;
                w00[j] = (1.f - fx) * (1.f - fy);
                w10[j] = fx * (1.f - fy);
                w01[j] = (1.f - fx) * fy;
                w11[j] = fx * fy;
                lbase[j] = (y0 - (ty - 2)) * SCOLS + x0;   // slot row 2..6
            }
        }
    }

    size_t plane = (size_t)OUT_N * OUT_N;
    const float* xb = x + ((size_t)b * CHAN + c0) * plane;
    float* ob = out + ((size_t)b * CHAN + c0) * plane;
    size_t orow = (size_t)oy * OUT_N;

    #define STAGE(c, bufIdx)                                                     \
        do {                                                                     \
            const float* xc_ = xb + (size_t)(c) * plane;                         \
            _Pragma("unroll")                                                    \
            for (int k_ = 0; k_ < 4; ++k_)                                       \
                GLD16(xc_ + goff[k_],                                            \
                      &tile[(bufIdx) * BUFS + (k_ * 256 + wb0) * 4]);            \
        } while (0)

    STAGE(0, 0);
    STAGE(1, 1);

    for (int c = 0; c < CPB; ++c) {
        // Counted wait for stage(c): younger ops are stage(c+1) [4] and
        // stores(c-1) [4] (stores issue in the gather phase).
        // c=0: only stage(1) -> 4.  c=CPB-1: only stores(c-1) -> 4.  else 8.
        if (c == 0 || c == CPB - 1) asm volatile("s_waitcnt vmcnt(4)" ::: "memory");
        else                        asm volatile("s_waitcnt vmcnt(8)" ::: "memory");
        __builtin_amdgcn_s_barrier();          // all waves' c-loads landed
        __builtin_amdgcn_sched_barrier(0);

        const float* tb_ = &tile[(c & 1) * BUFS];
        float* oc = ob + (size_t)c * plane;
        #pragma unroll
        for (int k = 0; k < 4; ++k) {
            float vv0, vv1;
            {
                int j = k * 2;
                int lb = lbase[j];
                vv0 = w00[j] * tb_[lb] + w10[j] * tb_[lb + 1]
                    + w01[j] * tb_[lb + SCOLS] + w11[j] * tb_[lb + SCOLS + 1];
            }
            {
                int j = k * 2 + 1;
                int lb = lbase[j];
                vv1 = w00[j] * tb_[lb] + w10[j] * tb_[lb + 1]
                    + w01[j] * tb_[lb + SCOLS] + w11[j] * tb_[lb + SCOLS + 1];
            }
            v2f st; st.x = vv0; st.y = vv1;
            __builtin_nontemporal_store(st, (v2f*)(oc + orow + cb + 128 * k));
        }

        __builtin_amdgcn_sched_barrier(0);
        __builtin_amdgcn_s_barrier();          // all waves done reading buf[c&1]
        __builtin_amdgcn_sched_barrier(0);

        if (c + 2 < CPB) STAGE(c + 2, c & 1);  // DMA overwrite now safe
    }
    #undef STAGE
}

extern "C" void kernel_launch(void* const* d_in, const int* in_sizes, int n_in,
                              void* d_out, int out_size, void* d_ws, size_t ws_size,
                              hipStream_t stream) {
    (void)in_sizes; (void)n_in; (void)d_ws; (void)ws_size; (void)out_size;
    const float* x  = (const float*)d_in[0];   // (8,32,512,512)
    const float* xs = (const float*)d_in[1];   // (8,1,256,256)
    // d_in[2] = gauss_kernel: recomputed analytically (separable form).

    float* out = (float*)d_out;
    const size_t XS_OUT = (size_t)BATCH * CHAN * OUT_N * OUT_N;  // 67,108,864
    float* gup = out + XS_OUT;  // output 1: grid_up (8,2,512,512)

    // Scratch lives in the x_sampled region of d_out; fully overwritten by
    // sample_kernel (which runs after its consumers).
    float* H    = out;                     // 8*4*316*256 = 2,588,672 floats
    float* g256 = out + 4u * 1024 * 1024;  // 8*2*256*256 = 1,048,576 floats

    hipLaunchKernelGGL(hpass_kernel, dim3(BATCH * GLOB_N), dim3(256), 0, stream, xs, H);
    hipLaunchKernelGGL(vpass_kernel, dim3(BATCH * GRID_N), dim3(256), 0, stream, H, g256);
    hipLaunchKernelGGL(upsample_kernel, dim3(BATCH * OUT_N * OUT_N / 256), dim3(256), 0, stream,
                       g256, gup);
    const int SBLOCKS = BATCH * (CHAN / CPB) * (OUT_N / STH);   // 2048
    hipLaunchKernelGGL(sample_kernel, dim3(SBLOCKS), dim3(256), 0, stream, x, gup, out);
}

// Round 12
// 134.781 us; speedup vs baseline: 1.1083x; 1.0305x over previous
//
#include <hip/hip_runtime.h>
#include <math.h>

#define GRID_N 256
#define PADN   30
#define GLOB_N 316   // GRID_N + 2*PADN
#define KS     61    // 2*PADN + 1
#define OUT_N  512
#define BATCH  8
#define CHAN   32
#define CPB    8     // channels per sampler block

// Sampler tile: 8 full-width output rows (8x512) per 512-thread block.
// Deformation bound (analytic, input-independent): pyf in [oy-1.26, oy+1.26],
// gx,gy in [-1,1] => y0 in [oy-2, oy+1], x0 in [0,511].
// Staged window: rows ty-2..ty+9 (12 rows x 512 cols = 24 KB, CONTIGUOUS).
// Read amplification 12/8 = 1.5x (was 2.0x at 4-row bands).
#define STH    8                  // output rows per block
#define SSR    12                 // staged rows
#define SCOLS  512
#define BUFS   6208               // floats per buffer (12*512 + 64 pad)
// LDS: 2*BUFS*4 = 49,664 B -> 3 blocks/CU x 8 waves = 24 waves/CU

typedef float v2f __attribute__((ext_vector_type(2)));

#define GLD16(gaddr, laddr)                                                       \
    __builtin_amdgcn_global_load_lds(                                             \
        (const __attribute__((address_space(1))) void*)(gaddr),                   \
        (__attribute__((address_space(3))) void*)(laddr), 16, 0, 0)

// Two 1D Gaussian factor vectors into LDS (first KS threads).
// make_gaussian(a=1,b=0.5,fwhm1=100,fwhm2=25) is exactly separable:
// kernel[u][v] = g1[u]*g1[v] - 0.5*g2[u]*g2[v].
__device__ __forceinline__ void compute_weights(float* w1, float* w2) {
    int t = threadIdx.x;
    if (t < KS) {
        double d  = (double)(t - PADN);
        double r2 = d * d;
        const double c = 2.772588722239781;  // 4*ln(2)
        w1[t] = (float)exp(-c * r2 / 10000.0); // fwhm1 = 100
        w2[t] = (float)exp(-c * r2 / 625.0);   // fwhm2 = 25
    }
}

// Horizontal separable pass. One block per (batch, global row gi in [0,316)).
__global__ __launch_bounds__(256) void hpass_kernel(const float* __restrict__ xs,
                                                    float* __restrict__ H) {
    __shared__ float srow[GLOB_N];
    __shared__ float w1[KS], w2[KS];
    int b  = blockIdx.x / GLOB_N;
    int gi = blockIdx.x % GLOB_N;
    int t  = threadIdx.x;

    compute_weights(w1, w2);

    int iy = gi - PADN;
    iy = iy < 0 ? 0 : (iy > GRID_N - 1 ? GRID_N - 1 : iy);
    const float* src = xs + ((size_t)b * GRID_N + iy) * GRID_N;
    for (int j = t; j < GLOB_N; j += 256) {
        int ix = j - PADN;
        ix = ix < 0 ? 0 : (ix > GRID_N - 1 ? GRID_N - 1 : ix);
        srow[j] = src[ix];
    }
    __syncthreads();

    float a1 = 0.f, a2 = 0.f, a3 = 0.f, a4 = 0.f;
    for (int v = 0; v < KS; ++v) {
        float s  = srow[t + v];
        float cc = (float)(t + v - PADN) * (1.0f / 255.0f);
        float cs = cc * s;
        float cw1 = w1[v], cw2 = w2[v];
        a1 += cw1 * s;
        a2 += cw2 * s;
        a3 += cw1 * cs;
        a4 += cw2 * cs;
    }
    size_t cst  = (size_t)GLOB_N * GRID_N;
    size_t base = ((size_t)(b * 4) * GLOB_N + gi) * GRID_N + t;
    H[base]           = a1;
    H[base + cst]     = a2;
    H[base + 2 * cst] = a3;
    H[base + 3 * cst] = a4;
}

// Vertical pass + normalize + clip. XCD-swizzled (chunk 256 = one batch/XCD).
__global__ __launch_bounds__(256) void vpass_kernel(const float* __restrict__ H,
                                                    float* __restrict__ g256) {
    __shared__ float w1[KS], w2[KS];
    int bid = (int)blockIdx.x;
    bid = (bid & 7) * 256 + (bid >> 3);
    int b = bid >> 8;
    int y = bid & 255;
    int t = threadIdx.x;

    compute_weights(w1, w2);
    __syncthreads();

    const float* Hb = H + (size_t)b * 4 * GLOB_N * GRID_N;
    size_t cst = (size_t)GLOB_N * GRID_N;

    float s1 = 0.f, s2 = 0.f, sx1 = 0.f, sx2 = 0.f, sy1 = 0.f, sy2 = 0.f;
    for (int u = 0; u < KS; ++u) {
        size_t off = (size_t)(y + u) * GRID_N + t;
        float h1 = Hb[off];
        float h2 = Hb[off + cst];
        float h3 = Hb[off + 2 * cst];
        float h4 = Hb[off + 3 * cst];
        float cw1 = w1[u], cw2 = w2[u];
        float cc = (float)(y + u - PADN) * (1.0f / 255.0f);
        s1  += cw1 * h1;
        s2  += cw2 * h2;
        sx1 += cw1 * h3;
        sx2 += cw2 * h4;
        sy1 += cw1 * (cc * h1);
        sy2 += cw2 * (cc * h2);
    }
    float p  = s1 - 0.5f * s2;
    float xf = (sx1 - 0.5f * sx2) / p;
    float yf = (sy1 - 0.5f * sy2) / p;
    float xg = fminf(fmaxf(xf * 2.0f - 1.0f, -1.0f), 1.0f);
    float yg = fminf(fmaxf(yf * 2.0f - 1.0f, -1.0f), 1.0f);

    size_t o = (size_t)(b * 2) * GRID_N * GRID_N + (size_t)y * GRID_N + t;
    g256[o] = xg;
    g256[o + (size_t)GRID_N * GRID_N] = yg;
}

// 2x bilinear upsample, jax.image.resize half-pixel semantics.
__global__ __launch_bounds__(256) void upsample_kernel(const float* __restrict__ g256,
                                                       float* __restrict__ gup) {
    int idx = blockIdx.x * 256 + threadIdx.x;
    int ox = idx & (OUT_N - 1);
    int oy = (idx >> 9) & (OUT_N - 1);
    int b  = idx >> 18;

    float sx = 0.5f * (float)ox - 0.25f;
    float sy = 0.5f * (float)oy - 0.25f;
    float fxf = floorf(sx), fyf = floorf(sy);
    int x0 = (int)fxf, y0 = (int)fyf;
    float fx = sx - fxf, fy = sy - fyf;
    int x0c = x0 < 0 ? 0 : x0;
    int x1c = x0 + 1 > GRID_N - 1 ? GRID_N - 1 : x0 + 1;
    int y0c = y0 < 0 ? 0 : y0;
    int y1c = y0 + 1 > GRID_N - 1 ? GRID_N - 1 : y0 + 1;

    for (int c = 0; c < 2; ++c) {
        const float* g = g256 + ((size_t)(b * 2 + c)) * GRID_N * GRID_N;
        float v00 = g[y0c * GRID_N + x0c];
        float v10 = g[y0c * GRID_N + x1c];
        float v01 = g[y1c * GRID_N + x0c];
        float v11 = g[y1c * GRID_N + x1c];
        float v = (v00 * (1.f - fx) + v10 * fx) * (1.f - fy)
                + (v01 * (1.f - fx) + v11 * fx) * fy;
        gup[((size_t)(b * 2 + c)) * OUT_N * OUT_N + (size_t)oy * OUT_N + ox] = v;
    }
}

// grid_sample bilinear via CONTIGUOUS DMA-staged row bands.
// 512-thread block = 8 full-width output rows x CPB channels. Per channel:
// one contiguous 24 KB fetch (12 rows x 512) via 3 global_load_lds calls per
// wave, LDS gather, dwordx2 nontemporal stores. Counted vmcnt, raw barriers.
__global__ __launch_bounds__(512) void sample_kernel(const float* __restrict__ x,
                                                     const float* __restrict__ gup,
                                                     float* __restrict__ out) {
    __shared__ float tile[2 * BUFS];   // 49,664 B

    int bid = (int)blockIdx.x;
    // 2048 blocks; chunk 256 -> XCD k owns batch k; row-groups sweep fastest.
    bid = (bid & 7) * 256 + (bid >> 3);
    int b  = bid >> 8;
    int cg = (bid >> 6) & 3;
    int rg = bid & 63;
    int ty = rg * STH;
    int c0 = cg * CPB;

    int t  = threadIdx.x;
    int r  = t >> 6;          // output row 0..7 within the band
    int cb = (t & 63) * 2;    // column pair base

    // ---- per-thread DMA source offsets (channel-invariant, contiguous) ----
    // slot = k*512 + t (k=0..2): srow = 4k + (t>>7), scol = (t&127)*4.
    int goff[3];
    {
        int baserow = ty - 2 + (t >> 7);
        int scol = (t & 127) * 4;
        #pragma unroll
        for (int k = 0; k < 3; ++k) {
            int rr = baserow + 4 * k;
            rr = rr < 0 ? 0 : (rr > OUT_N - 1 ? OUT_N - 1 : rr);
            goff[k] = rr * OUT_N + scol;
        }
    }
    int wb0 = (t & ~63);       // wave-uniform slot base

    // ---- per-px bilinear weights + LDS base indices (channel-invariant) ----
    // Thread's 8 px: ox = 128*k + cb + h, oy = ty + r.
    float w00[8], w10[8], w01[8], w11[8];
    int lbase[8];
    int oy = ty + r;
    {
        size_t gplane = (size_t)OUT_N * OUT_N;
        size_t grow = (size_t)(b * 2) * gplane + (size_t)oy * OUT_N;
        float by = -1.0f + (float)oy * (2.0f / 511.0f);
        #pragma unroll
        for (int k = 0; k < 4; ++k) {
            #pragma unroll
            for (int h = 0; h < 2; ++h) {
                int j = k * 2 + h;
                int ox = 128 * k + cb + h;
                float gxu = gup[grow + ox];
                float gyu = gup[grow + ox + gplane];
                float bx = -1.0f + (float)ox * (2.0f / 511.0f);
                float gx = (49.0f * bx + gxu) * 0.02f;
                float gy = (49.0f * by + gyu) * 0.02f;
                float pxf = (gx + 1.0f) * 255.5f;  // in [0,511]
                float pyf = (gy + 1.0f) * 255.5f;
                float fx0 = floorf(pxf), fy0 = floorf(pyf);
                int x0 = (int)fx0, y0 = (int)fy0;
                float fx = pxf - fx0, fy = pyf - fy0;
                w00[j] = (1.f - fx) * (1.f - fy);
                w10[j] = fx * (1.f - fy);
                w01[j] = (1.f - fx) * fy;
                w11[j] = fx * fy;
                lbase[j] = (y0 - (ty - 2)) * SCOLS + x0;   // staged rows 0..11
            }
        }
    }

    size_t plane = (size_t)OUT_N * OUT_N;
    const float* xb = x + ((size_t)b * CHAN + c0) * plane;
    float* ob = out + ((size_t)b * CHAN + c0) * plane;
    size_t orow = (size_t)oy * OUT_N;

    #define STAGE(c, bufIdx)                                                     \
        do {                                                                     \
            const float* xc_ = xb + (size_t)(c) * plane;                         \
            _Pragma("unroll")                                                    \
            for (int k_ = 0; k_ < 3; ++k_)                                       \
                GLD16(xc_ + goff[k_],                                            \
                      &tile[(bufIdx) * BUFS + (k_ * 512 + wb0) * 4]);            \
        } while (0)

    STAGE(0, 0);
    STAGE(1, 1);

    for (int c = 0; c < CPB; ++c) {
        // Counted wait for stage(c) [3 loads]; younger outstanding vmem:
        // steady/mid: stores(c-1)[4] + stage(c+1)[3] = 7;
        // c=0: only stage(1) -> 3; c=CPB-1: only stores(c-1) -> 4.
        if (c == 0)                 asm volatile("s_waitcnt vmcnt(3)" ::: "memory");
        else if (c == CPB - 1)      asm volatile("s_waitcnt vmcnt(4)" ::: "memory");
        else                        asm volatile("s_waitcnt vmcnt(7)" ::: "memory");
        __builtin_amdgcn_s_barrier();          // all waves' c-loads landed
        __builtin_amdgcn_sched_barrier(0);

        const float* tb_ = &tile[(c & 1) * BUFS];
        float* oc = ob + (size_t)c * plane;
        #pragma unroll
        for (int k = 0; k < 4; ++k) {
            float vv0, vv1;
            {
                int j = k * 2;
                int lb = lbase[j];
                vv0 = w00[j] * tb_[lb] + w10[j] * tb_[lb + 1]
                    + w01[j] * tb_[lb + SCOLS] + w11[j] * tb_[lb + SCOLS + 1];
            }
            {
                int j = k * 2 + 1;
                int lb = lbase[j];
                vv1 = w00[j] * tb_[lb] + w10[j] * tb_[lb + 1]
                    + w01[j] * tb_[lb + SCOLS] + w11[j] * tb_[lb + SCOLS + 1];
            }
            v2f st; st.x = vv0; st.y = vv1;
            __builtin_nontemporal_store(st, (v2f*)(oc + orow + cb + 128 * k));
        }

        __builtin_amdgcn_sched_barrier(0);
        __builtin_amdgcn_s_barrier();          // all waves done reading buf[c&1]
        __builtin_amdgcn_sched_barrier(0);

        if (c + 2 < CPB) STAGE(c + 2, c & 1);  // DMA overwrite now safe
    }
    #undef STAGE
}

extern "C" void kernel_launch(void* const* d_in, const int* in_sizes, int n_in,
                              void* d_out, int out_size, void* d_ws, size_t ws_size,
                              hipStream_t stream) {
    (void)in_sizes; (void)n_in; (void)d_ws; (void)ws_size; (void)out_size;
    const float* x  = (const float*)d_in[0];   // (8,32,512,512)
    const float* xs = (const float*)d_in[1];   // (8,1,256,256)
    // d_in[2] = gauss_kernel: recomputed analytically (separable form).

    float* out = (float*)d_out;
    const size_t XS_OUT = (size_t)BATCH * CHAN * OUT_N * OUT_N;  // 67,108,864
    float* gup = out + XS_OUT;  // output 1: grid_up (8,2,512,512)

    // Scratch lives in the x_sampled region of d_out; fully overwritten by
    // sample_kernel (which runs after its consumers).
    float* H    = out;                     // 8*4*316*256 = 2,588,672 floats
    float* g256 = out + 4u * 1024 * 1024;  // 8*2*256*256 = 1,048,576 floats

    hipLaunchKernelGGL(hpass_kernel, dim3(BATCH * GLOB_N), dim3(256), 0, stream, xs, H);
    hipLaunchKernelGGL(vpass_kernel, dim3(BATCH * GRID_N), dim3(256), 0, stream, H, g256);
    hipLaunchKernelGGL(upsample_kernel, dim3(BATCH * OUT_N * OUT_N / 256), dim3(256), 0, stream,
                       g256, gup);
    const int SBLOCKS = BATCH * (CHAN / CPB) * (OUT_N / STH);   // 2048
    hipLaunchKernelGGL(sample_kernel, dim3(SBLOCKS), dim3(512), 0, stream, x, gup, out);
}